// Round 2
// baseline (831.261 us; speedup 1.0000x reference)
//
#include <hip/hip_runtime.h>
#include <hip/hip_bf16.h>
#include <cstdint>
#include <cstddef>

#define E_ 8
#define M_ 1024
#define H_ 2048
#define I2_ 4096
#define INTER_ 2048

typedef __attribute__((ext_vector_type(8))) __bf16 bf16x8;
typedef __attribute__((ext_vector_type(4))) float f32x4;

__device__ __forceinline__ unsigned short f2bf(float x) {
  union { float f; unsigned u; } v; v.f = x;
  unsigned r = v.u + 0x7fffu + ((v.u >> 16) & 1u);   // RNE
  return (unsigned short)(r >> 16);
}

// pack two f32 -> (lo,hi) bf16 pair; maps to v_cvt_pk_bf16_f32 on gfx950
__device__ __forceinline__ unsigned pk2(float lo, float hi) {
  __hip_bfloat162 h = __float22bfloat162_rn(make_float2(lo, hi));
  union { __hip_bfloat162 h2; unsigned u; } c; c.h2 = h; return c.u;
}

// LDS B tile (OLD f32-B path): dword (= bf16 k-pair) at [kp][r].
__device__ __forceinline__ int bofs(int kp, int r) {
  int f = (20 * ((kp >> 2) & 3)) ^ ((kp & 1) << 4);
  return kp * 128 + (r ^ f);
}

// ---------------- f32 -> bf16 elementwise (dispatched) ----------------
__global__ void k_cvt(const float* __restrict__ src, unsigned short* __restrict__ dst, int n4) {
  int i = blockIdx.x * blockDim.x + threadIdx.x;
  int stride = gridDim.x * blockDim.x;
  const float4* s4 = (const float4*)src;
  ushort4* d4 = (ushort4*)dst;
  for (; i < n4; i += stride) {
    float4 v = s4[i];
    ushort4 o;
    o.x = f2bf(v.x); o.y = f2bf(v.y); o.z = f2bf(v.z); o.w = f2bf(v.w);
    d4[i] = o;
  }
}

// ---------------- weight transpose+convert: W[e][k][n] f32 -> Wp[e][n'][k] bf16 ----
// PERM=1: n' rows permuted so that within each 32-col block, rows [0,16) are the
// gate (even) columns in order and rows [16,32) the up (odd) columns — matching
// the GEMM1 epilogue's rearranged-column space.
template<int PERM>
__global__ __launch_bounds__(256) void k_wt(
    const float* __restrict__ W, unsigned short* __restrict__ Wp, int Kd, int Nd) {
  __shared__ float tt[64][65];
  const int tid = threadIdx.x;
  const int e = blockIdx.z;
  const int nb0 = blockIdx.x * 64;
  const int k0 = blockIdx.y * 64;
  const float* We = W + (size_t)e * Kd * Nd;

  // load 64x64 f32 tile, coalesced float4
  #pragma unroll
  for (int i = 0; i < 4; ++i) {
    int r = (tid >> 4) + 16 * i;      // k row within tile
    int c4 = tid & 15;                // float4 col
    float4 v = *(const float4*)(We + (size_t)(k0 + r) * Nd + nb0 + 4 * c4);
    tt[r][4 * c4 + 0] = v.x;
    tt[r][4 * c4 + 1] = v.y;
    tt[r][4 * c4 + 2] = v.z;
    tt[r][4 * c4 + 3] = v.w;
  }
  __syncthreads();

  // write transposed bf16: each thread owns one n-column, 16 k values
  int n = tid >> 2;                   // 0..63
  int kc = (tid & 3) * 16;            // k offset within tile
  int nglob = nb0 + n;
  int nrow;
  if (PERM) {
    int b = nglob >> 5, w = nglob & 31;
    nrow = 32 * b + ((w & 1) ? 16 + (w >> 1) : (w >> 1));
  } else {
    nrow = nglob;
  }
  unsigned o[8];
  #pragma unroll
  for (int j = 0; j < 8; ++j)
    o[j] = pk2(tt[kc + 2 * j][n], tt[kc + 2 * j + 1][n]);
  unsigned short* dst = Wp + (size_t)e * Nd * Kd + (size_t)nrow * Kd + k0 + kc;
  *(uint4*)(dst) = *(uint4*)&o[0];
  *(uint4*)(dst + 8) = *(uint4*)&o[4];
}

// ---------------- NT MFMA GEMM: C = A(bf16 MxK) * Bp^T (Bp bf16 NxK) ----------------
// Both operands K-contiguous bf16; both staged by global_load_lds(16B) with the
// pre-swizzled-global-source XOR pattern; fragments read via single ds_read_b128.
template<int ACT, int N, int K>
__global__ __launch_bounds__(256) void k_gemm_nt(
    const unsigned short* __restrict__ A,    // E x M x K   (bf16)
    const unsigned short* __restrict__ B,    // E x N x K   (bf16; ACT: rows permuted)
    const float* __restrict__ bias,          // E x N  (original column order)
    unsigned short* __restrict__ ActOut,     // E x M x N/2 (ACT)
    float* __restrict__ Out)                 // E x M x N   (!ACT)
{
  __shared__ unsigned short la[128 * 64];
  __shared__ unsigned short lb[128 * 64];
  const int tid = threadIdx.x;
  const int lane = tid & 63;
  const int wv = tid >> 6;
  const int wm = wv & 1, wn = wv >> 1;
  const int e = blockIdx.z;
  const int n0 = blockIdx.x * 128;
  const int m0 = blockIdx.y * 128;
  const unsigned short* Ae = A + (size_t)e * M_ * K + (size_t)m0 * K;
  const unsigned short* Be = B + (size_t)e * N * K + (size_t)n0 * K;

  // staging: slot s holds row m=s>>3, chunk j=(s&7)^(m&7) (swizzle baked into gsrc)
  const unsigned short* ga[4];
  const unsigned short* gb[4];
  int seg[4];
  #pragma unroll
  for (int t = 0; t < 4; ++t) {
    int s = (wv * 4 + t) * 64 + lane;
    int m = s >> 3;
    int j = (s & 7) ^ (m & 7);
    ga[t] = Ae + (size_t)m * K + j * 8;
    gb[t] = Be + (size_t)m * K + j * 8;
    seg[t] = (wv * 4 + t) * 1024;
  }

  const int c = lane & 15;
  const int q = lane >> 4;

  f32x4 acc[4][4];
  const f32x4 zero = {0.f, 0.f, 0.f, 0.f};
  #pragma unroll
  for (int i = 0; i < 4; ++i)
    #pragma unroll
    for (int j = 0; j < 4; ++j) acc[i][j] = zero;

  const int KT = K / 64;
  for (int kt = 0; kt < KT; ++kt) {
    #pragma unroll
    for (int t = 0; t < 4; ++t) {
      __builtin_amdgcn_global_load_lds(
          (const __attribute__((address_space(1))) void*)(const void*)(ga[t] + kt * 64),
          (__attribute__((address_space(3))) void*)(void*)((char*)la + seg[t]), 16, 0, 0);
      __builtin_amdgcn_global_load_lds(
          (const __attribute__((address_space(1))) void*)(const void*)(gb[t] + kt * 64),
          (__attribute__((address_space(3))) void*)(void*)((char*)lb + seg[t]), 16, 0, 0);
    }
    __syncthreads();

    #pragma unroll
    for (int ks = 0; ks < 2; ++ks) {
      bf16x8 av[4], bv[4];
      #pragma unroll
      for (int mi = 0; mi < 4; ++mi) {
        int row = wm * 64 + mi * 16 + c;
        int slot = row * 8 + ((ks * 4 + q) ^ (c & 7));
        av[mi] = *(const bf16x8*)(la + slot * 8);
      }
      #pragma unroll
      for (int ni = 0; ni < 4; ++ni) {
        int row = wn * 64 + ni * 16 + c;
        int slot = row * 8 + ((ks * 4 + q) ^ (c & 7));
        bv[ni] = *(const bf16x8*)(lb + slot * 8);
      }
      #pragma unroll
      for (int mi = 0; mi < 4; ++mi)
        #pragma unroll
        for (int ni = 0; ni < 4; ++ni)
          acc[mi][ni] = __builtin_amdgcn_mfma_f32_16x16x32_bf16(av[mi], bv[ni], acc[mi][ni], 0, 0, 0);
    }
    __syncthreads();
  }

  if (ACT) {
    unsigned short* ActE = ActOut + (size_t)e * M_ * (N / 2);
    const float* be = bias + (size_t)e * N;
    int colbase = n0 + wn * 64;
    #pragma unroll
    for (int p = 0; p < 2; ++p) {
      int rgc = colbase + 32 * p + c;              // gate column in rearranged gu
      int norig = (rgc & ~31) | (c << 1);          // original interleaved column
      float bg_ = be[norig];
      float bu_ = be[norig + 1];
      int acol = ((rgc >> 5) << 4) + c;            // activated column
      #pragma unroll
      for (int mi = 0; mi < 4; ++mi) {
        int rowb = m0 + wm * 64 + mi * 16 + q * 4;
        #pragma unroll
        for (int r = 0; r < 4; ++r) {
          float g = acc[mi][2 * p][r] + bg_;
          float u = acc[mi][2 * p + 1][r] + bu_;
          g = fminf(g, 7.0f);
          u = fminf(fmaxf(u, -7.0f), 7.0f);
          float glu = g / (1.0f + __expf(-1.702f * g));
          float a = (u + 1.0f) * glu;
          ActE[(size_t)(rowb + r) * (N / 2) + acol] = f2bf(a);
        }
      }
    }
  } else {
    float* OutE = Out + (size_t)e * M_ * N;
    const float* be = bias + (size_t)e * N;
    #pragma unroll
    for (int ni = 0; ni < 4; ++ni) {
      int col = n0 + wn * 64 + ni * 16 + c;
      float bb = be[col];
      #pragma unroll
      for (int mi = 0; mi < 4; ++mi) {
        int rowb = m0 + wm * 64 + mi * 16 + q * 4;
        #pragma unroll
        for (int r = 0; r < 4; ++r)
          OutE[(size_t)(rowb + r) * N + col] = acc[mi][ni][r] + bb;
      }
    }
  }
}

// ---------------- OLD path: MFMA GEMM with on-the-fly f32 B conversion -------------
template<int ACT, int N, int K>
__global__ __launch_bounds__(256) void k_gemm(
    const unsigned short* __restrict__ A,
    const float* __restrict__ Bf,
    const float* __restrict__ bias,
    unsigned short* __restrict__ ActOut,
    float* __restrict__ Out)
{
  __shared__ unsigned short la[128 * 64];
  __shared__ unsigned lb32[32 * 128];
  const int tid = threadIdx.x;
  const int lane = tid & 63;
  const int wv = tid >> 6;
  const int wm = wv & 1, wn = wv >> 1;
  const int e = blockIdx.z;
  const int n0 = blockIdx.x * 128;
  const int m0 = blockIdx.y * 128;
  const unsigned short* Ae = A + (size_t)e * M_ * K + (size_t)m0 * K;
  const float* Be = Bf + (size_t)e * K * N + n0;

  const unsigned short* ga[4];
  int segb[4];
  #pragma unroll
  for (int t = 0; t < 4; ++t) {
    int s = (wv * 4 + t) * 64 + lane;
    int m = s >> 3;
    int j = (s & 7) ^ (m & 7);
    ga[t] = Ae + (size_t)m * K + j * 8;
    segb[t] = (wv * 4 + t) * 1024;
  }

  int kpb, colb, rg;
  if (ACT) {
    kpb = tid >> 4;
    int g = tid & 15;
    colb = 8 * g;
    rg = 32 * (g >> 2) + 4 * (g & 3);
  } else {
    kpb = tid >> 5;
    colb = 4 * (tid & 31);
    rg = colb;
  }
  const float* bg = Be + (size_t)(2 * kpb) * N + colb;

  const int c = lane & 15;
  const int q = lane >> 4;

  f32x4 acc[4][4];
  const f32x4 zero = {0.f, 0.f, 0.f, 0.f};
  #pragma unroll
  for (int i = 0; i < 4; ++i)
    #pragma unroll
    for (int j = 0; j < 4; ++j) acc[i][j] = zero;

  #define LD4(p, off) (*(const float4*)((p) + (off)))

  float4 pb[8];
  {
    const float* p = bg;
    if (ACT) {
      pb[0] = LD4(p, 0);                    pb[1] = LD4(p, 4);
      pb[2] = LD4(p, (size_t)N);            pb[3] = LD4(p, (size_t)N + 4);
      pb[4] = LD4(p, (size_t)32 * N);       pb[5] = LD4(p, (size_t)32 * N + 4);
      pb[6] = LD4(p, (size_t)33 * N);       pb[7] = LD4(p, (size_t)33 * N + 4);
    } else {
      #pragma unroll
      for (int uu = 0; uu < 4; ++uu) {
        pb[2 * uu]     = LD4(p, (size_t)(16 * uu) * N);
        pb[2 * uu + 1] = LD4(p, (size_t)(16 * uu + 1) * N);
      }
    }
  }

  const int KT = K / 64;
  for (int kt = 0; kt < KT; ++kt) {
    #pragma unroll
    for (int t = 0; t < 4; ++t) {
      __builtin_amdgcn_global_load_lds(
          (const __attribute__((address_space(1))) void*)(const void*)(ga[t] + kt * 64),
          (__attribute__((address_space(3))) void*)(void*)((char*)la + segb[t]), 16, 0, 0);
    }
    if (ACT) {
      #pragma unroll
      for (int uu = 0; uu < 2; ++uu) {
        int kp = kpb + 16 * uu;
        float4 a0 = pb[4 * uu], a1 = pb[4 * uu + 1], b0 = pb[4 * uu + 2], b1 = pb[4 * uu + 3];
        uint4 gv, uv;
        gv.x = pk2(a0.x, b0.x); gv.y = pk2(a0.z, b0.z); gv.z = pk2(a1.x, b1.x); gv.w = pk2(a1.z, b1.z);
        uv.x = pk2(a0.y, b0.y); uv.y = pk2(a0.w, b0.w); uv.z = pk2(a1.w, b1.w); uv.w = pk2(a1.w, b1.w);
        uv.z = pk2(a1.y, b1.y);
        *(uint4*)&lb32[bofs(kp, rg)] = gv;
        *(uint4*)&lb32[bofs(kp, rg + 16)] = uv;
      }
    } else {
      #pragma unroll
      for (int uu = 0; uu < 4; ++uu) {
        int kp = kpb + 8 * uu;
        float4 a = pb[2 * uu], b = pb[2 * uu + 1];
        uint4 v;
        v.x = pk2(a.x, b.x); v.y = pk2(a.y, b.y); v.z = pk2(a.z, b.z); v.w = pk2(a.w, b.w);
        *(uint4*)&lb32[bofs(kp, rg)] = v;
      }
    }
    __syncthreads();

    if (kt + 1 < KT) {
      const float* p = bg + (size_t)(kt + 1) * 64 * N;
      if (ACT) {
        pb[0] = LD4(p, 0);                    pb[1] = LD4(p, 4);
        pb[2] = LD4(p, (size_t)N);            pb[3] = LD4(p, (size_t)N + 4);
        pb[4] = LD4(p, (size_t)32 * N);       pb[5] = LD4(p, (size_t)32 * N + 4);
        pb[6] = LD4(p, (size_t)33 * N);       pb[7] = LD4(p, (size_t)33 * N + 4);
      } else {
        #pragma unroll
        for (int uu = 0; uu < 4; ++uu) {
          pb[2 * uu]     = LD4(p, (size_t)(16 * uu) * N);
          pb[2 * uu + 1] = LD4(p, (size_t)(16 * uu + 1) * N);
        }
      }
    }

    #pragma unroll
    for (int ks = 0; ks < 2; ++ks) {
      bf16x8 av[4], bv[4];
      #pragma unroll
      for (int mi = 0; mi < 4; ++mi) {
        int row = wm * 64 + mi * 16 + c;
        int slot = row * 8 + ((ks * 4 + q) ^ (c & 7));
        av[mi] = *(const bf16x8*)(la + slot * 8);
      }
      #pragma unroll
      for (int ni = 0; ni < 4; ++ni) {
        int r = wn * 64 + ni * 16 + c;
        union { unsigned u[4]; bf16x8 v; } t;
        #pragma unroll
        for (int jp = 0; jp < 4; ++jp)
          t.u[jp] = lb32[bofs(ks * 16 + q * 4 + jp, r)];
        bv[ni] = t.v;
      }
      #pragma unroll
      for (int mi = 0; mi < 4; ++mi)
        #pragma unroll
        for (int ni = 0; ni < 4; ++ni)
          acc[mi][ni] = __builtin_amdgcn_mfma_f32_16x16x32_bf16(av[mi], bv[ni], acc[mi][ni], 0, 0, 0);
    }
    __syncthreads();
  }
  #undef LD4

  if (ACT) {
    unsigned short* ActE = ActOut + (size_t)e * M_ * (N / 2);
    const float* be = bias + (size_t)e * N;
    int colbase = n0 + wn * 64;
    #pragma unroll
    for (int p = 0; p < 2; ++p) {
      int rgc = colbase + 32 * p + c;
      int norig = (rgc & ~31) | (c << 1);
      float bg_ = be[norig];
      float bu_ = be[norig + 1];
      int acol = ((rgc >> 5) << 4) + c;
      #pragma unroll
      for (int mi = 0; mi < 4; ++mi) {
        int rowb = m0 + wm * 64 + mi * 16 + q * 4;
        #pragma unroll
        for (int r = 0; r < 4; ++r) {
          float g = acc[mi][2 * p][r] + bg_;
          float u = acc[mi][2 * p + 1][r] + bu_;
          g = fminf(g, 7.0f);
          u = fminf(fmaxf(u, -7.0f), 7.0f);
          float glu = g / (1.0f + __expf(-1.702f * g));
          float a = (u + 1.0f) * glu;
          ActE[(size_t)(rowb + r) * (N / 2) + acol] = f2bf(a);
        }
      }
    }
  } else {
    float* OutE = Out + (size_t)e * M_ * N;
    const float* be = bias + (size_t)e * N;
    #pragma unroll
    for (int ni = 0; ni < 4; ++ni) {
      int col = n0 + wn * 64 + ni * 16 + c;
      float bb = be[col];
      #pragma unroll
      for (int mi = 0; mi < 4; ++mi) {
        int rowb = m0 + wm * 64 + mi * 16 + q * 4;
        #pragma unroll
        for (int r = 0; r < 4; ++r)
          OutE[(size_t)(rowb + r) * N + col] = acc[mi][ni][r] + bb;
      }
    }
  }
}

// ---------------- scratch-free fallback (correct but slow) ----------------
__global__ __launch_bounds__(256) void k_naive(const float* __restrict__ disp,
    const float* __restrict__ w1, const float* __restrict__ w1b,
    const float* __restrict__ w2, const float* __restrict__ w2b,
    float* __restrict__ out) {
  __shared__ float xrow[H_];
  __shared__ float act[INTER_];
  int b = blockIdx.x;
  int e = b / M_;
  int m = b % M_;
  const float* x = disp + (size_t)(e * M_ + m) * H_;
  int tid = threadIdx.x;
  for (int k = tid; k < H_; k += 256) xrow[k] = x[k];
  __syncthreads();
  const float* w1e = w1 + (size_t)e * H_ * I2_;
  const float* b1e = w1b + (size_t)e * I2_;
  for (int jj = 0; jj < INTER_ / 256; ++jj) {
    int i = tid + jj * 256;
    float g = b1e[2 * i], u = b1e[2 * i + 1];
    for (int k = 0; k < H_; ++k) {
      float xv = xrow[k];
      g += xv * w1e[(size_t)k * I2_ + 2 * i];
      u += xv * w1e[(size_t)k * I2_ + 2 * i + 1];
    }
    g = fminf(g, 7.0f);
    u = fminf(fmaxf(u, -7.0f), 7.0f);
    float glu = g / (1.0f + __expf(-1.702f * g));
    act[i] = (u + 1.0f) * glu;
  }
  __syncthreads();
  const float* w2e = w2 + (size_t)e * INTER_ * H_;
  const float* b2e = w2b + (size_t)e * H_;
  float* oute = out + (size_t)(e * M_ + m) * H_;
  for (int jj = 0; jj < H_ / 256; ++jj) {
    int h = tid + jj * 256;
    float o = b2e[h];
    for (int i = 0; i < INTER_; ++i) o += act[i] * w2e[(size_t)i * H_ + h];
    oute[h] = o;
  }
}

extern "C" void kernel_launch(void* const* d_in, const int* in_sizes, int n_in,
                              void* d_out, int out_size, void* d_ws, size_t ws_size,
                              hipStream_t stream) {
  const float* disp = (const float*)d_in[0];
  const float* w1   = (const float*)d_in[1];
  const float* w1b  = (const float*)d_in[2];
  const float* w2   = (const float*)d_in[3];
  const float* w2b  = (const float*)d_in[4];
  float* out = (float*)d_out;

  const size_t nA   = (size_t)E_ * M_ * H_;        // 16.7M
  const size_t nAct = (size_t)E_ * M_ * INTER_;    // 16.7M
  const size_t nW1  = (size_t)E_ * I2_ * H_;       // 67.1M
  const size_t nW2  = (size_t)E_ * H_ * INTER_;    // 33.5M
  const size_t need_full = (nA + nAct + nW1 + nW2) * 2;  // 256 MiB
  const size_t need_old  = (nA + nAct) * 2;              // 67 MB

  if (ws_size >= need_full) {
    unsigned short* actb = (unsigned short*)d_ws;
    unsigned short* ab   = actb + nAct;
    unsigned short* w1p  = ab + nA;
    unsigned short* w2p  = w1p + nW1;

    k_cvt<<<4096, 256, 0, stream>>>(disp, ab, (int)(nA / 4));
    k_wt<1><<<dim3(I2_ / 64, H_ / 64, E_), 256, 0, stream>>>(w1, w1p, H_, I2_);
    k_wt<0><<<dim3(H_ / 64, INTER_ / 64, E_), 256, 0, stream>>>(w2, w2p, INTER_, H_);
    k_gemm_nt<1, I2_, H_><<<dim3(I2_ / 128, M_ / 128, E_), 256, 0, stream>>>(ab, w1p, w1b, actb, nullptr);
    k_gemm_nt<0, H_, INTER_><<<dim3(H_ / 128, M_ / 128, E_), 256, 0, stream>>>(actb, w2p, w2b, nullptr, out);
  } else if (ws_size >= need_old) {
    unsigned short* actb = (unsigned short*)d_ws;
    unsigned short* ab   = actb + nAct;

    k_cvt<<<4096, 256, 0, stream>>>(disp, ab, (int)(nA / 4));
    k_gemm<1, I2_, H_><<<dim3(I2_ / 128, M_ / 128, E_), 256, 0, stream>>>(ab, w1, w1b, actb, nullptr);
    k_gemm<0, H_, INTER_><<<dim3(H_ / 128, M_ / 128, E_), 256, 0, stream>>>(actb, w2, w2b, nullptr, out);
  } else {
    k_naive<<<E_ * M_, 256, 0, stream>>>(disp, w1, w1b, w2, w2b, out);
  }
}

// Round 3
// 820.774 us; speedup vs baseline: 1.0128x; 1.0128x over previous
//
#include <hip/hip_runtime.h>
#include <hip/hip_bf16.h>
#include <cstdint>
#include <cstddef>

#define E_ 8
#define M_ 1024
#define H_ 2048
#define I2_ 4096
#define INTER_ 2048

typedef __attribute__((ext_vector_type(8))) __bf16 bf16x8;
typedef __attribute__((ext_vector_type(4))) float f32x4;

__device__ __forceinline__ unsigned short f2bf(float x) {
  union { float f; unsigned u; } v; v.f = x;
  unsigned r = v.u + 0x7fffu + ((v.u >> 16) & 1u);   // RNE
  return (unsigned short)(r >> 16);
}

// pack two f32 -> (lo,hi) bf16 pair; maps to v_cvt_pk_bf16_f32 on gfx950
__device__ __forceinline__ unsigned pk2(float lo, float hi) {
  __hip_bfloat162 h = __float22bfloat162_rn(make_float2(lo, hi));
  union { __hip_bfloat162 h2; unsigned u; } c; c.h2 = h; return c.u;
}

// LDS B tile (OLD f32-B path): dword (= bf16 k-pair) at [kp][r].
__device__ __forceinline__ int bofs(int kp, int r) {
  int f = (20 * ((kp >> 2) & 3)) ^ ((kp & 1) << 4);
  return kp * 128 + (r ^ f);
}

// ---------------- f32 -> bf16 elementwise (dispatched) ----------------
__global__ void k_cvt(const float* __restrict__ src, unsigned short* __restrict__ dst, int n4) {
  int i = blockIdx.x * blockDim.x + threadIdx.x;
  int stride = gridDim.x * blockDim.x;
  const float4* s4 = (const float4*)src;
  ushort4* d4 = (ushort4*)dst;
  for (; i < n4; i += stride) {
    float4 v = s4[i];
    ushort4 o;
    o.x = f2bf(v.x); o.y = f2bf(v.y); o.z = f2bf(v.z); o.w = f2bf(v.w);
    d4[i] = o;
  }
}

// ---------------- weight transpose+convert: W[e][k][n] f32 -> Wp[e][n'][k] bf16 ----
// PERM=1: n' rows permuted so that within each 32-col block, rows [0,16) are the
// gate (even) columns in order and rows [16,32) the up (odd) columns — matching
// the GEMM1 epilogue's rearranged-column space.
template<int PERM>
__global__ __launch_bounds__(256) void k_wt(
    const float* __restrict__ W, unsigned short* __restrict__ Wp, int Kd, int Nd) {
  __shared__ float tt[64][65];
  const int tid = threadIdx.x;
  const int e = blockIdx.z;
  const int nb0 = blockIdx.x * 64;
  const int k0 = blockIdx.y * 64;
  const float* We = W + (size_t)e * Kd * Nd;

  // load 64x64 f32 tile, coalesced float4
  #pragma unroll
  for (int i = 0; i < 4; ++i) {
    int r = (tid >> 4) + 16 * i;      // k row within tile
    int c4 = tid & 15;                // float4 col
    float4 v = *(const float4*)(We + (size_t)(k0 + r) * Nd + nb0 + 4 * c4);
    tt[r][4 * c4 + 0] = v.x;
    tt[r][4 * c4 + 1] = v.y;
    tt[r][4 * c4 + 2] = v.z;
    tt[r][4 * c4 + 3] = v.w;
  }
  __syncthreads();

  // write transposed bf16: each thread owns one n-column, 16 k values
  int n = tid >> 2;                   // 0..63
  int kc = (tid & 3) * 16;            // k offset within tile
  int nglob = nb0 + n;
  int nrow;
  if (PERM) {
    int b = nglob >> 5, w = nglob & 31;
    nrow = 32 * b + ((w & 1) ? 16 + (w >> 1) : (w >> 1));
  } else {
    nrow = nglob;
  }
  unsigned o[8];
  #pragma unroll
  for (int j = 0; j < 8; ++j)
    o[j] = pk2(tt[kc + 2 * j][n], tt[kc + 2 * j + 1][n]);
  unsigned short* dst = Wp + (size_t)e * Nd * Kd + (size_t)nrow * Kd + k0 + kc;
  *(uint4*)(dst) = *(uint4*)&o[0];
  *(uint4*)(dst + 8) = *(uint4*)&o[4];
}

// ---------------- NT GEMM helpers: double-buffered stage + hoisted-addr compute ----
__device__ __forceinline__ void stage_tile(
    const unsigned short* const (&ga)[4], const unsigned short* const (&gb)[4],
    const int (&seg)[4], char* laB, char* lbB, int kt) {
  #pragma unroll
  for (int t = 0; t < 4; ++t) {
    __builtin_amdgcn_global_load_lds(
        (const __attribute__((address_space(1))) void*)(const void*)(ga[t] + kt * 64),
        (__attribute__((address_space(3))) void*)(void*)(laB + seg[t]), 16, 0, 0);
    __builtin_amdgcn_global_load_lds(
        (const __attribute__((address_space(1))) void*)(const void*)(gb[t] + kt * 64),
        (__attribute__((address_space(3))) void*)(void*)(lbB + seg[t]), 16, 0, 0);
  }
}

__device__ __forceinline__ void compute_tile(
    const unsigned short* laB, const unsigned short* lbB,
    const int (&slA)[2][4], const int (&slB)[2][4], f32x4 (&acc)[4][4]) {
  #pragma unroll
  for (int ks = 0; ks < 2; ++ks) {
    bf16x8 av[4], bv[4];
    #pragma unroll
    for (int mi = 0; mi < 4; ++mi) av[mi] = *(const bf16x8*)(laB + slA[ks][mi]);
    #pragma unroll
    for (int ni = 0; ni < 4; ++ni) bv[ni] = *(const bf16x8*)(lbB + slB[ks][ni]);
    #pragma unroll
    for (int mi = 0; mi < 4; ++mi)
      #pragma unroll
      for (int ni = 0; ni < 4; ++ni)
        acc[mi][ni] = __builtin_amdgcn_mfma_f32_16x16x32_bf16(av[mi], bv[ni], acc[mi][ni], 0, 0, 0);
  }
}

// ---------------- NT MFMA GEMM: C = A(bf16 MxK) * Bp^T (Bp bf16 NxK) ----------------
// Both operands K-contiguous bf16, staged by global_load_lds(16B) with the
// pre-swizzled-global-source XOR pattern; double-buffered LDS, stage(t+1)
// overlapped with compute(t); one vmcnt(0)+s_barrier per K-tile.
template<int ACT, int N, int K>
__global__ __launch_bounds__(256) void k_gemm_nt(
    const unsigned short* __restrict__ A,    // E x M x K   (bf16)
    const unsigned short* __restrict__ B,    // E x N x K   (bf16; ACT: rows permuted)
    const float* __restrict__ bias,          // E x N  (original column order)
    unsigned short* __restrict__ ActOut,     // E x M x N/2 (ACT)
    float* __restrict__ Out)                 // E x M x N   (!ACT)
{
  __shared__ unsigned short la[2][128 * 64];
  __shared__ unsigned short lb[2][128 * 64];
  const int tid = threadIdx.x;
  const int lane = tid & 63;
  const int wv = tid >> 6;
  const int wm = wv & 1, wn = wv >> 1;
  const int e = blockIdx.z;
  const int n0 = blockIdx.x * 128;
  const int m0 = blockIdx.y * 128;
  const unsigned short* Ae = A + (size_t)e * M_ * K + (size_t)m0 * K;
  const unsigned short* Be = B + (size_t)e * N * K + (size_t)n0 * K;

  // staging: slot s holds row m=s>>3, chunk j=(s&7)^(m&7) (swizzle baked into gsrc)
  const unsigned short* ga[4];
  const unsigned short* gb[4];
  int seg[4];
  #pragma unroll
  for (int t = 0; t < 4; ++t) {
    int s = (wv * 4 + t) * 64 + lane;
    int m = s >> 3;
    int j = (s & 7) ^ (m & 7);
    ga[t] = Ae + (size_t)m * K + j * 8;
    gb[t] = Be + (size_t)m * K + j * 8;
    seg[t] = (wv * 4 + t) * 1024;
  }

  const int c = lane & 15;
  const int q = lane >> 4;

  // hoisted fragment LDS element-offsets (loop-invariant across kt)
  int slA[2][4], slB[2][4];
  #pragma unroll
  for (int ks = 0; ks < 2; ++ks) {
    #pragma unroll
    for (int i = 0; i < 4; ++i) {
      int xorj = (ks * 4 + q) ^ (c & 7);
      slA[ks][i] = ((wm * 64 + i * 16 + c) * 8 + xorj) * 8;
      slB[ks][i] = ((wn * 64 + i * 16 + c) * 8 + xorj) * 8;
    }
  }

  f32x4 acc[4][4];
  const f32x4 zero = {0.f, 0.f, 0.f, 0.f};
  #pragma unroll
  for (int i = 0; i < 4; ++i)
    #pragma unroll
    for (int j = 0; j < 4; ++j) acc[i][j] = zero;

  const int KT = K / 64;   // even (K=2048 -> 32)
  stage_tile(ga, gb, seg, (char*)&la[0][0], (char*)&lb[0][0], 0);
  asm volatile("s_waitcnt vmcnt(0)\n\ts_barrier" ::: "memory");

  for (int kt = 0; kt < KT; kt += 2) {
    if (kt + 1 < KT)
      stage_tile(ga, gb, seg, (char*)&la[1][0], (char*)&lb[1][0], kt + 1);
    __builtin_amdgcn_s_setprio(1);
    compute_tile(&la[0][0], &lb[0][0], slA, slB, acc);
    __builtin_amdgcn_s_setprio(0);
    asm volatile("s_waitcnt vmcnt(0)\n\ts_barrier" ::: "memory");

    if (kt + 2 < KT)
      stage_tile(ga, gb, seg, (char*)&la[0][0], (char*)&lb[0][0], kt + 2);
    __builtin_amdgcn_s_setprio(1);
    compute_tile(&la[1][0], &lb[1][0], slA, slB, acc);
    __builtin_amdgcn_s_setprio(0);
    asm volatile("s_waitcnt vmcnt(0)\n\ts_barrier" ::: "memory");
  }

  if (ACT) {
    unsigned short* ActE = ActOut + (size_t)e * M_ * (N / 2);
    const float* be = bias + (size_t)e * N;
    int colbase = n0 + wn * 64;
    #pragma unroll
    for (int p = 0; p < 2; ++p) {
      int rgc = colbase + 32 * p + c;              // gate column in rearranged gu
      int norig = (rgc & ~31) | (c << 1);          // original interleaved column
      float bg_ = be[norig];
      float bu_ = be[norig + 1];
      int acol = ((rgc >> 5) << 4) + c;            // activated column
      #pragma unroll
      for (int mi = 0; mi < 4; ++mi) {
        int rowb = m0 + wm * 64 + mi * 16 + q * 4;
        #pragma unroll
        for (int r = 0; r < 4; ++r) {
          float g = acc[mi][2 * p][r] + bg_;
          float u = acc[mi][2 * p + 1][r] + bu_;
          g = fminf(g, 7.0f);
          u = fminf(fmaxf(u, -7.0f), 7.0f);
          float glu = g / (1.0f + __expf(-1.702f * g));
          float a = (u + 1.0f) * glu;
          ActE[(size_t)(rowb + r) * (N / 2) + acol] = f2bf(a);
        }
      }
    }
  } else {
    float* OutE = Out + (size_t)e * M_ * N;
    const float* be = bias + (size_t)e * N;
    #pragma unroll
    for (int ni = 0; ni < 4; ++ni) {
      int col = n0 + wn * 64 + ni * 16 + c;
      float bb = be[col];
      #pragma unroll
      for (int mi = 0; mi < 4; ++mi) {
        int rowb = m0 + wm * 64 + mi * 16 + q * 4;
        #pragma unroll
        for (int r = 0; r < 4; ++r)
          OutE[(size_t)(rowb + r) * N + col] = acc[mi][ni][r] + bb;
      }
    }
  }
}

// ---------------- OLD path: MFMA GEMM with on-the-fly f32 B conversion -------------
template<int ACT, int N, int K>
__global__ __launch_bounds__(256) void k_gemm(
    const unsigned short* __restrict__ A,
    const float* __restrict__ Bf,
    const float* __restrict__ bias,
    unsigned short* __restrict__ ActOut,
    float* __restrict__ Out)
{
  __shared__ unsigned short la[128 * 64];
  __shared__ unsigned lb32[32 * 128];
  const int tid = threadIdx.x;
  const int lane = tid & 63;
  const int wv = tid >> 6;
  const int wm = wv & 1, wn = wv >> 1;
  const int e = blockIdx.z;
  const int n0 = blockIdx.x * 128;
  const int m0 = blockIdx.y * 128;
  const unsigned short* Ae = A + (size_t)e * M_ * K + (size_t)m0 * K;
  const float* Be = Bf + (size_t)e * K * N + n0;

  const unsigned short* ga[4];
  int segb[4];
  #pragma unroll
  for (int t = 0; t < 4; ++t) {
    int s = (wv * 4 + t) * 64 + lane;
    int m = s >> 3;
    int j = (s & 7) ^ (m & 7);
    ga[t] = Ae + (size_t)m * K + j * 8;
    segb[t] = (wv * 4 + t) * 1024;
  }

  int kpb, colb, rg;
  if (ACT) {
    kpb = tid >> 4;
    int g = tid & 15;
    colb = 8 * g;
    rg = 32 * (g >> 2) + 4 * (g & 3);
  } else {
    kpb = tid >> 5;
    colb = 4 * (tid & 31);
    rg = colb;
  }
  const float* bg = Be + (size_t)(2 * kpb) * N + colb;

  const int c = lane & 15;
  const int q = lane >> 4;

  f32x4 acc[4][4];
  const f32x4 zero = {0.f, 0.f, 0.f, 0.f};
  #pragma unroll
  for (int i = 0; i < 4; ++i)
    #pragma unroll
    for (int j = 0; j < 4; ++j) acc[i][j] = zero;

  #define LD4(p, off) (*(const float4*)((p) + (off)))

  float4 pb[8];
  {
    const float* p = bg;
    if (ACT) {
      pb[0] = LD4(p, 0);                    pb[1] = LD4(p, 4);
      pb[2] = LD4(p, (size_t)N);            pb[3] = LD4(p, (size_t)N + 4);
      pb[4] = LD4(p, (size_t)32 * N);       pb[5] = LD4(p, (size_t)32 * N + 4);
      pb[6] = LD4(p, (size_t)33 * N);       pb[7] = LD4(p, (size_t)33 * N + 4);
    } else {
      #pragma unroll
      for (int uu = 0; uu < 4; ++uu) {
        pb[2 * uu]     = LD4(p, (size_t)(16 * uu) * N);
        pb[2 * uu + 1] = LD4(p, (size_t)(16 * uu + 1) * N);
      }
    }
  }

  const int KT = K / 64;
  for (int kt = 0; kt < KT; ++kt) {
    #pragma unroll
    for (int t = 0; t < 4; ++t) {
      __builtin_amdgcn_global_load_lds(
          (const __attribute__((address_space(1))) void*)(const void*)(ga[t] + kt * 64),
          (__attribute__((address_space(3))) void*)(void*)((char*)la + segb[t]), 16, 0, 0);
    }
    if (ACT) {
      #pragma unroll
      for (int uu = 0; uu < 2; ++uu) {
        int kp = kpb + 16 * uu;
        float4 a0 = pb[4 * uu], a1 = pb[4 * uu + 1], b0 = pb[4 * uu + 2], b1 = pb[4 * uu + 3];
        uint4 gv, uv;
        gv.x = pk2(a0.x, b0.x); gv.y = pk2(a0.z, b0.z); gv.z = pk2(a1.x, b1.x); gv.w = pk2(a1.z, b1.z);
        uv.x = pk2(a0.y, b0.y); uv.y = pk2(a0.w, b0.w); uv.z = pk2(a1.y, b1.y); uv.w = pk2(a1.w, b1.w);
        *(uint4*)&lb32[bofs(kp, rg)] = gv;
        *(uint4*)&lb32[bofs(kp, rg + 16)] = uv;
      }
    } else {
      #pragma unroll
      for (int uu = 0; uu < 4; ++uu) {
        int kp = kpb + 8 * uu;
        float4 a = pb[2 * uu], b = pb[2 * uu + 1];
        uint4 v;
        v.x = pk2(a.x, b.x); v.y = pk2(a.y, b.y); v.z = pk2(a.z, b.z); v.w = pk2(a.w, b.w);
        *(uint4*)&lb32[bofs(kp, rg)] = v;
      }
    }
    __syncthreads();

    if (kt + 1 < KT) {
      const float* p = bg + (size_t)(kt + 1) * 64 * N;
      if (ACT) {
        pb[0] = LD4(p, 0);                    pb[1] = LD4(p, 4);
        pb[2] = LD4(p, (size_t)N);            pb[3] = LD4(p, (size_t)N + 4);
        pb[4] = LD4(p, (size_t)32 * N);       pb[5] = LD4(p, (size_t)32 * N + 4);
        pb[6] = LD4(p, (size_t)33 * N);       pb[7] = LD4(p, (size_t)33 * N + 4);
      } else {
        #pragma unroll
        for (int uu = 0; uu < 4; ++uu) {
          pb[2 * uu]     = LD4(p, (size_t)(16 * uu) * N);
          pb[2 * uu + 1] = LD4(p, (size_t)(16 * uu + 1) * N);
        }
      }
    }

    #pragma unroll
    for (int ks = 0; ks < 2; ++ks) {
      bf16x8 av[4], bv[4];
      #pragma unroll
      for (int mi = 0; mi < 4; ++mi) {
        int row = wm * 64 + mi * 16 + c;
        int slot = row * 8 + ((ks * 4 + q) ^ (c & 7));
        av[mi] = *(const bf16x8*)(la + slot * 8);
      }
      #pragma unroll
      for (int ni = 0; ni < 4; ++ni) {
        int r = wn * 64 + ni * 16 + c;
        union { unsigned u[4]; bf16x8 v; } t;
        #pragma unroll
        for (int jp = 0; jp < 4; ++jp)
          t.u[jp] = lb32[bofs(ks * 16 + q * 4 + jp, r)];
        bv[ni] = t.v;
      }
      #pragma unroll
      for (int mi = 0; mi < 4; ++mi)
        #pragma unroll
        for (int ni = 0; ni < 4; ++ni)
          acc[mi][ni] = __builtin_amdgcn_mfma_f32_16x16x32_bf16(av[mi], bv[ni], acc[mi][ni], 0, 0, 0);
    }
    __syncthreads();
  }
  #undef LD4

  if (ACT) {
    unsigned short* ActE = ActOut + (size_t)e * M_ * (N / 2);
    const float* be = bias + (size_t)e * N;
    int colbase = n0 + wn * 64;
    #pragma unroll
    for (int p = 0; p < 2; ++p) {
      int rgc = colbase + 32 * p + c;
      int norig = (rgc & ~31) | (c << 1);
      float bg_ = be[norig];
      float bu_ = be[norig + 1];
      int acol = ((rgc >> 5) << 4) + c;
      #pragma unroll
      for (int mi = 0; mi < 4; ++mi) {
        int rowb = m0 + wm * 64 + mi * 16 + q * 4;
        #pragma unroll
        for (int r = 0; r < 4; ++r) {
          float g = acc[mi][2 * p][r] + bg_;
          float u = acc[mi][2 * p + 1][r] + bu_;
          g = fminf(g, 7.0f);
          u = fminf(fmaxf(u, -7.0f), 7.0f);
          float glu = g / (1.0f + __expf(-1.702f * g));
          float a = (u + 1.0f) * glu;
          ActE[(size_t)(rowb + r) * (N / 2) + acol] = f2bf(a);
        }
      }
    }
  } else {
    float* OutE = Out + (size_t)e * M_ * N;
    const float* be = bias + (size_t)e * N;
    #pragma unroll
    for (int ni = 0; ni < 4; ++ni) {
      int col = n0 + wn * 64 + ni * 16 + c;
      float bb = be[col];
      #pragma unroll
      for (int mi = 0; mi < 4; ++mi) {
        int rowb = m0 + wm * 64 + mi * 16 + q * 4;
        #pragma unroll
        for (int r = 0; r < 4; ++r)
          OutE[(size_t)(rowb + r) * N + col] = acc[mi][ni][r] + bb;
      }
    }
  }
}

// ---------------- scratch-free fallback (correct but slow) ----------------
__global__ __launch_bounds__(256) void k_naive(const float* __restrict__ disp,
    const float* __restrict__ w1, const float* __restrict__ w1b,
    const float* __restrict__ w2, const float* __restrict__ w2b,
    float* __restrict__ out) {
  __shared__ float xrow[H_];
  __shared__ float act[INTER_];
  int b = blockIdx.x;
  int e = b / M_;
  int m = b % M_;
  const float* x = disp + (size_t)(e * M_ + m) * H_;
  int tid = threadIdx.x;
  for (int k = tid; k < H_; k += 256) xrow[k] = x[k];
  __syncthreads();
  const float* w1e = w1 + (size_t)e * H_ * I2_;
  const float* b1e = w1b + (size_t)e * I2_;
  for (int jj = 0; jj < INTER_ / 256; ++jj) {
    int i = tid + jj * 256;
    float g = b1e[2 * i], u = b1e[2 * i + 1];
    for (int k = 0; k < H_; ++k) {
      float xv = xrow[k];
      g += xv * w1e[(size_t)k * I2_ + 2 * i];
      u += xv * w1e[(size_t)k * I2_ + 2 * i + 1];
    }
    g = fminf(g, 7.0f);
    u = fminf(fmaxf(u, -7.0f), 7.0f);
    float glu = g / (1.0f + __expf(-1.702f * g));
    act[i] = (u + 1.0f) * glu;
  }
  __syncthreads();
  const float* w2e = w2 + (size_t)e * INTER_ * H_;
  const float* b2e = w2b + (size_t)e * H_;
  float* oute = out + (size_t)(e * M_ + m) * H_;
  for (int jj = 0; jj < H_ / 256; ++jj) {
    int h = tid + jj * 256;
    float o = b2e[h];
    for (int i = 0; i < INTER_; ++i) o += act[i] * w2e[(size_t)i * H_ + h];
    oute[h] = o;
  }
}

extern "C" void kernel_launch(void* const* d_in, const int* in_sizes, int n_in,
                              void* d_out, int out_size, void* d_ws, size_t ws_size,
                              hipStream_t stream) {
  const float* disp = (const float*)d_in[0];
  const float* w1   = (const float*)d_in[1];
  const float* w1b  = (const float*)d_in[2];
  const float* w2   = (const float*)d_in[3];
  const float* w2b  = (const float*)d_in[4];
  float* out = (float*)d_out;

  const size_t nA   = (size_t)E_ * M_ * H_;        // 16.7M
  const size_t nAct = (size_t)E_ * M_ * INTER_;    // 16.7M
  const size_t nW1  = (size_t)E_ * I2_ * H_;       // 67.1M
  const size_t nW2  = (size_t)E_ * H_ * INTER_;    // 33.5M
  const size_t need_full = (nA + nAct + nW1 + nW2) * 2;  // 256 MiB
  const size_t need_old  = (nA + nAct) * 2;              // 67 MB

  if (ws_size >= need_full) {
    unsigned short* actb = (unsigned short*)d_ws;
    unsigned short* ab   = actb + nAct;
    unsigned short* w1p  = ab + nA;
    unsigned short* w2p  = w1p + nW1;

    k_cvt<<<4096, 256, 0, stream>>>(disp, ab, (int)(nA / 4));
    k_wt<1><<<dim3(I2_ / 64, H_ / 64, E_), 256, 0, stream>>>(w1, w1p, H_, I2_);
    k_wt<0><<<dim3(H_ / 64, INTER_ / 64, E_), 256, 0, stream>>>(w2, w2p, INTER_, H_);
    k_gemm_nt<1, I2_, H_><<<dim3(I2_ / 128, M_ / 128, E_), 256, 0, stream>>>(ab, w1p, w1b, actb, nullptr);
    k_gemm_nt<0, H_, INTER_><<<dim3(H_ / 128, M_ / 128, E_), 256, 0, stream>>>(actb, w2p, w2b, nullptr, out);
  } else if (ws_size >= need_old) {
    unsigned short* actb = (unsigned short*)d_ws;
    unsigned short* ab   = actb + nAct;

    k_cvt<<<4096, 256, 0, stream>>>(disp, ab, (int)(nA / 4));
    k_gemm<1, I2_, H_><<<dim3(I2_ / 128, M_ / 128, E_), 256, 0, stream>>>(ab, w1, w1b, actb, nullptr);
    k_gemm<0, H_, INTER_><<<dim3(H_ / 128, M_ / 128, E_), 256, 0, stream>>>(actb, w2, w2b, nullptr, out);
  } else {
    k_naive<<<E_ * M_, 256, 0, stream>>>(disp, w1, w1b, w2, w2b, out);
  }
}